// Round 3
// baseline (616.838 us; speedup 1.0000x reference)
//
#include <hip/hip_runtime.h>

// GraphConv: B=16, S=50000, FIN=FOUT=16, T=64, E=8M
// R3: R2 post-mortem — hist/place/pull were ALL LDS-atomic-unit bound
// (~3.8 cyc per atomic lane-op per CU; 43M lane-ops ~= 265us of 338us).
// Replace every per-element LDS atomic with ballot-based ranking
// (ballots -> equal-key mask -> popcount rank; group leaders do plain
// wave-private LDS histogram RMW). 512-row buckets; pull uses 2
// threads/row (even/odd ranks) to cut gather tail imbalance.
#define BNUM 16
#define NCOL 800000   // S*FIN
#define NROW 800000   // S*FOUT
#define RPB  512      // rows per bucket
#define NBIN 1563     // ceil(NROW/RPB)
#define PBINS 2048    // padded bin count (11-bit digit)
#define PR   8192     // edges per k_part/k_hist block
#define CAP  6144     // pull LDS sort capacity (mean 5118, +14 sigma)

// ---- bf16 <-> f32 helpers (bit-exact RNE) ----
__device__ __forceinline__ unsigned short f2bf(float f) {
    unsigned u = __float_as_uint(f);
    unsigned r = (u + 0x7fffu + ((u >> 16) & 1u)) >> 16;   // round-nearest-even
    return (unsigned short)r;
}
__device__ __forceinline__ float bf2f(unsigned short h) {
    return __uint_as_float(((unsigned)h) << 16);
}

// ballot-based equal-key mask + rank within group (wave-parallel, no atomics)
template <int BITS>
__device__ __forceinline__ void brank(unsigned key, bool v, int lane,
                                      int& rank, int& gsz) {
    unsigned long long vm = __ballot(v);
    unsigned long long eq = ~0ull;
#pragma unroll
    for (int b = 0; b < BITS; ++b) {
        unsigned long long bb = __ballot((key >> b) & 1u);
        eq &= ((key >> b) & 1u) ? bb : ~bb;
    }
    eq &= vm;
    rank = __popcll(eq & ((1ull << lane) - 1ull));
    gsz  = __popcll(eq);
}

// x [16][800000] f32 (b-major) -> xT [800000][16] bf16 (c-major, 32B per c)
__global__ __launch_bounds__(256) void k_transpose_x(const float* __restrict__ x,
                                                     unsigned* __restrict__ xT) {
    int c = blockIdx.x * 256 + threadIdx.x;
    if (c >= NCOL) return;
    unsigned p[8];
#pragma unroll
    for (int b = 0; b < 8; ++b) {
        float lo = x[(size_t)(2 * b)     * NCOL + c];
        float hi = x[(size_t)(2 * b + 1) * NCOL + c];
        p[b] = (unsigned)f2bf(lo) | ((unsigned)f2bf(hi) << 16);
    }
    uint4* dst = reinterpret_cast<uint4*>(xT + (size_t)c * 8);
    dst[0] = make_uint4(p[0], p[1], p[2], p[3]);
    dst[1] = make_uint4(p[4], p[5], p[6], p[7]);
}

// Ballot-based per-wave histogram of row bins (atomic-free per element).
__global__ __launch_bounds__(1024) void k_hist(const int* __restrict__ rows,
                                               unsigned* __restrict__ gcount,
                                               int E) {
    __shared__ unsigned short h16[16][PBINS];   // 64KB, wave-private rows
    int tid = threadIdx.x, lane = tid & 63, wv = tid >> 6;
    unsigned* hw = (unsigned*)h16;
    for (int i = tid; i < 16 * PBINS / 2; i += 1024) hw[i] = 0u;
    __syncthreads();
    int c0 = blockIdx.x * PR;
#pragma unroll
    for (int c = 0; c < 8; ++c) {
        int idx = c0 + c * 1024 + tid;
        bool v = idx < E;
        unsigned key = 0u;
        if (v) key = (unsigned)__builtin_nontemporal_load(rows + idx) >> 9;
        int rank, gsz;
        brank<11>(key, v, lane, rank, gsz);
        if (v && rank == 0)
            h16[wv][key] = (unsigned short)(h16[wv][key] + (unsigned)gsz);
    }
    __syncthreads();
    for (int b = tid; b < PBINS; b += 1024) {
        unsigned s = 0;
#pragma unroll
        for (int ww = 0; ww < 16; ++ww) s += h16[ww][b];
        if (s) atomicAdd(&gcount[b], s);
    }
}

// Exclusive scan of 2048 counts (single block), offs + cursor init.
__global__ __launch_bounds__(1024) void k_scan(const unsigned* __restrict__ gcount,
                                               unsigned* __restrict__ offs,
                                               unsigned* __restrict__ cursor) {
    __shared__ unsigned wsum[16];
    int t = threadIdx.x;
    unsigned a0 = gcount[2 * t], a1 = gcount[2 * t + 1];
    unsigned ts = a0 + a1, incl = ts;
    for (int off = 1; off < 64; off <<= 1) {
        unsigned n = __shfl_up(incl, off, 64);
        if ((t & 63) >= off) incl += n;
    }
    if ((t & 63) == 63) wsum[t >> 6] = incl;
    __syncthreads();
    unsigned pre = 0;
    for (int k = 0; k < (t >> 6); ++k) pre += wsum[k];
    unsigned ex = pre + incl - ts;
    offs[2 * t] = ex;       offs[2 * t + 1] = ex + a0;
    cursor[2 * t] = ex;     cursor[2 * t + 1] = ex + a0;
    if (t == 1023) offs[2048] = pre + incl;
}

// Ballot multisplit by bin = row>>9 (atomic-free ranking). Edges in
// registers; phase A counts, block scan, phase B places into LDS sorted
// order, run-contiguous flush. recA = col|type<<20, recB = row & 511.
__global__ __launch_bounds__(1024) void k_part(const int* __restrict__ rows,
                                               const int* __restrict__ cols,
                                               const int* __restrict__ et,
                                               unsigned* __restrict__ cursor,
                                               unsigned* __restrict__ recA,
                                               unsigned short* __restrict__ recB,
                                               int E) {
    __shared__ unsigned short h16[16][PBINS];   // 64KB wave-private hist/cursor
    __shared__ unsigned srtP[PR];               // 32KB payload (col|type)
    __shared__ unsigned srtK[PR];               // 32KB raw row
    __shared__ unsigned short lofs[PBINS];      // 4KB block-local offsets
    __shared__ unsigned gadj[PBINS];            // 8KB gbase - lofs
    __shared__ unsigned wsum[16];

    int tid = threadIdx.x, lane = tid & 63, wv = tid >> 6;
    int c0 = blockIdx.x * PR;
    unsigned* hw = (unsigned*)h16;
    for (int i = tid; i < 16 * PBINS / 2; i += 1024) hw[i] = 0u;
    __syncthreads();

    unsigned er[8], ec[8];
#pragma unroll
    for (int c = 0; c < 8; ++c) {
        int idx = c0 + c * 1024 + tid;
        if (idx < E) {
            int r  = __builtin_nontemporal_load(rows + idx);
            int cc = __builtin_nontemporal_load(cols + idx);
            int ty = __builtin_nontemporal_load(et + idx);
            er[c] = (unsigned)r;
            ec[c] = (unsigned)cc | ((unsigned)ty << 20);
        } else {
            er[c] = 0xFFFFFFFFu;
        }
    }

    // phase A
#pragma unroll
    for (int c = 0; c < 8; ++c) {
        bool v = er[c] != 0xFFFFFFFFu;
        unsigned key = (er[c] >> 9) & (PBINS - 1);
        int rank, gsz;
        brank<11>(key, v, lane, rank, gsz);
        if (v && rank == 0)
            h16[wv][key] = (unsigned short)(h16[wv][key] + (unsigned)gsz);
    }
    __syncthreads();

    // per-bin wave prefix + block scan + global reservation
    {
        int b0 = 2 * tid, b1 = 2 * tid + 1;
        unsigned t0 = 0, t1 = 0;
#pragma unroll
        for (int ww = 0; ww < 16; ++ww) {
            unsigned a = h16[ww][b0]; h16[ww][b0] = (unsigned short)t0; t0 += a;
            unsigned b = h16[ww][b1]; h16[ww][b1] = (unsigned short)t1; t1 += b;
        }
        unsigned ts = t0 + t1, incl = ts;
        for (int off = 1; off < 64; off <<= 1) {
            unsigned n = __shfl_up(incl, off, 64);
            if ((tid & 63) >= off) incl += n;
        }
        if ((tid & 63) == 63) wsum[tid >> 6] = incl;
        __syncthreads();
        unsigned pre = 0;
        for (int k = 0; k < (tid >> 6); ++k) pre += wsum[k];
        unsigned ex = pre + incl - ts;
        lofs[b0] = (unsigned short)ex;
        lofs[b1] = (unsigned short)(ex + t0);
        if (t0) gadj[b0] = atomicAdd(&cursor[b0], t0) - ex;
        if (t1) gadj[b1] = atomicAdd(&cursor[b1], t1) - (ex + t0);
#pragma unroll
        for (int ww = 0; ww < 16; ++ww) {      // cur = lofs + wave prefix
            h16[ww][b0] = (unsigned short)(h16[ww][b0] + ex);
            h16[ww][b1] = (unsigned short)(h16[ww][b1] + ex + t0);
        }
    }
    __syncthreads();

    // phase B: replay, place into LDS sorted order
#pragma unroll
    for (int c = 0; c < 8; ++c) {
        bool v = er[c] != 0xFFFFFFFFu;
        unsigned key = (er[c] >> 9) & (PBINS - 1);
        int rank, gsz;
        brank<11>(key, v, lane, rank, gsz);
        unsigned cur = h16[wv][key];
        if (v && rank == 0)
            h16[wv][key] = (unsigned short)(cur + (unsigned)gsz);
        if (v) {
            unsigned d = cur + (unsigned)rank;
            srtP[d] = ec[c];
            srtK[d] = er[c];
        }
    }
    __syncthreads();

    // flush: consecutive LDS slots within a bin run -> consecutive global dst
    int tot = min(PR, E - c0);
    for (int j = tid; j < tot; j += 1024) {
        unsigned rr = srtK[j], key = rr >> 9;
        unsigned dst = gadj[key] + (unsigned)j;
        __builtin_nontemporal_store(srtP[j], recA + dst);
        __builtin_nontemporal_store((unsigned short)(rr & 511u), recB + dst);
    }
}

__device__ __forceinline__ void fma8(float* a, float wt, uint4 v, int base) {
    a[base + 0] += wt * bf2f((unsigned short)(v.x & 0xffffu));
    a[base + 1] += wt * bf2f((unsigned short)(v.x >> 16));
    a[base + 2] += wt * bf2f((unsigned short)(v.y & 0xffffu));
    a[base + 3] += wt * bf2f((unsigned short)(v.y >> 16));
    a[base + 4] += wt * bf2f((unsigned short)(v.z & 0xffffu));
    a[base + 5] += wt * bf2f((unsigned short)(v.z >> 16));
    a[base + 6] += wt * bf2f((unsigned short)(v.w & 0xffffu));
    a[base + 7] += wt * bf2f((unsigned short)(v.w >> 16));
}

// One block per 512-row bucket: ballot counting-sort by lrow (atomic-free),
// then 2 threads/row (even/odd ranks) register accumulate, LDS combine,
// coalesced store.
__global__ __launch_bounds__(1024) void k_pull(const unsigned* __restrict__ offs,
                                               const unsigned* __restrict__ recA,
                                               const unsigned short* __restrict__ recB,
                                               const float* __restrict__ wt_tab,
                                               const unsigned* __restrict__ xT,
                                               float* __restrict__ out) {
    __shared__ unsigned short h16[16][RPB];    // 16KB wave-private hist/cursor
    __shared__ unsigned srt[CAP];              // 24KB sorted payload
    __shared__ unsigned ptr_[RPB + 1];         // row offsets (totals stash first)
    __shared__ float buf[RPB * 17];            // 34.8KB combine buffer
    __shared__ unsigned wsum[8];

    int tid = threadIdx.x, lane = tid & 63, wv = tid >> 6;
    int b   = blockIdx.x;
    int beg = (int)offs[b];
    int end = (int)offs[b + 1];
    int n   = min(end - beg, CAP);
    int nr  = (n + 1023) >> 10;                // load rounds (<=6)

    unsigned* hw = (unsigned*)h16;
    for (int i = tid; i < 16 * RPB / 2; i += 1024) hw[i] = 0u;
    __syncthreads();

    unsigned pc[6]; unsigned short plr[6];
#pragma unroll
    for (int c = 0; c < 6; ++c) {
        plr[c] = 0xFFFFu;
        if (c < nr) {
            int idx = c * 1024 + tid;
            if (idx < n) {
                pc[c]  = __builtin_nontemporal_load(recA + beg + idx);
                plr[c] = __builtin_nontemporal_load(recB + beg + idx);
            }
        }
    }

    // phase A: ballot histogram by lrow (9 bits)
    for (int c = 0; c < nr; ++c) {
        bool v = plr[c] != 0xFFFFu;
        unsigned key = plr[c] & (RPB - 1u);
        int rank, gsz;
        brank<9>(key, v, lane, rank, gsz);
        if (v && rank == 0)
            h16[wv][key] = (unsigned short)(h16[wv][key] + (unsigned)gsz);
    }
    __syncthreads();

    // scan 512 bins (threads 0..511): wave prefix into h16, totals -> ptr_
    if (tid < RPB) {
        unsigned t0 = 0;
#pragma unroll
        for (int ww = 0; ww < 16; ++ww) {
            unsigned a = h16[ww][tid]; h16[ww][tid] = (unsigned short)t0; t0 += a;
        }
        unsigned incl = t0;
        for (int off = 1; off < 64; off <<= 1) {
            unsigned m = __shfl_up(incl, off, 64);
            if ((tid & 63) >= off) incl += m;
        }
        if ((tid & 63) == 63) wsum[tid >> 6] = incl;
        ptr_[tid] = incl - t0;                 // wave-local exclusive, fix below
    }
    __syncthreads();
    if (tid < RPB) {
        unsigned pre = 0;
        for (int k = 0; k < (tid >> 6); ++k) pre += wsum[k];
        unsigned ex = ptr_[tid] + pre;         // block-exclusive offset
        // total for this bin = h16[15][tid] (prefix before w15) + w15 count;
        // recover total from neighbor: next bin's ex  — instead just rebuild:
        ptr_[tid] = ex;
#pragma unroll
        for (int ww = 0; ww < 16; ++ww)
            h16[ww][tid] = (unsigned short)(h16[ww][tid] + ex);
        if (tid == RPB - 1) ptr_[RPB] = (unsigned)n;   // grand total = n
    }
    __syncthreads();

    // phase B: replay, place into LDS sorted order
    for (int c = 0; c < nr; ++c) {
        bool v = plr[c] != 0xFFFFu;
        unsigned key = plr[c] & (RPB - 1u);
        int rank, gsz;
        brank<9>(key, v, lane, rank, gsz);
        unsigned cur = h16[wv][key];
        if (v && rank == 0)
            h16[wv][key] = (unsigned short)(cur + (unsigned)gsz);
        if (v) srt[cur + (unsigned)rank] = pc[c];
    }
    __syncthreads();

    // gather: 2 threads per row (even/odd ranks), register accumulate
    int r = tid & (RPB - 1), h = tid >> 9;
    float a[16];
#pragma unroll
    for (int k = 0; k < 16; ++k) a[k] = 0.f;
    {
        int p0 = (int)ptr_[r] + h;
        int p1 = (int)ptr_[r + 1];
        uint4 lo = make_uint4(0, 0, 0, 0), hi = lo;
        unsigned u = 0u;
        int p = p0;
        if (p < p1) {
            u = srt[p];
            const uint4* q = reinterpret_cast<const uint4*>(xT + (size_t)(u & 0xFFFFFu) * 8);
            lo = q[0]; hi = q[1];
        }
        while (p < p1) {
            int pn = p + 2;
            unsigned un = 0u;
            uint4 lon = make_uint4(0, 0, 0, 0), hin = lon;
            if (pn < p1) {
                un = srt[pn];
                const uint4* qn = reinterpret_cast<const uint4*>(xT + (size_t)(un & 0xFFFFFu) * 8);
                lon = qn[0]; hin = qn[1];
            }
            float wt = wt_tab[u >> 20];
            fma8(a, wt, lo, 0);
            fma8(a, wt, hi, 8);
            u = un; lo = lon; hi = hin; p = pn;
        }
    }
    if (h == 1) {
#pragma unroll
        for (int k = 0; k < 16; ++k) buf[r * 17 + k] = a[k];
    }
    __syncthreads();
    if (h == 0) {
        int gr = b * RPB + r;
        if (gr < NROW) {
#pragma unroll
            for (int k = 0; k < 16; ++k)
                __builtin_nontemporal_store(a[k] + buf[r * 17 + k],
                                            out + (size_t)k * NROW + gr);
        }
    }

    // overflow safety (statistically never): atomic top-up after store
    if (end - beg > CAP) {
        __syncthreads();
        for (int i = beg + CAP + tid; i < end; i += 1024) {
            unsigned uu = recA[i];
            unsigned lr = recB[i];
            int gr = b * RPB + (int)lr;
            float wt = wt_tab[uu >> 20];
            const uint4* q = reinterpret_cast<const uint4*>(xT + (size_t)(uu & 0xFFFFFu) * 8);
            uint4 vlo = q[0], vhi = q[1];
            float tmp[16];
#pragma unroll
            for (int k = 0; k < 16; ++k) tmp[k] = 0.f;
            fma8(tmp, wt, vlo, 0);
            fma8(tmp, wt, vhi, 8);
#pragma unroll
            for (int k = 0; k < 16; ++k)
                atomicAdd(out + (size_t)k * NROW + gr, tmp[k]);
        }
    }
}

// ---------------- fallback path (old atomic scatter, needs only 51.2MB) ----

__global__ __launch_bounds__(256) void k_scatter(const int* __restrict__ rows,
                                                 const int* __restrict__ cols,
                                                 const int* __restrict__ et,
                                                 const float* __restrict__ w,
                                                 const unsigned* __restrict__ xT,
                                                 unsigned short* __restrict__ outT,
                                                 int E) {
    long long tid = (long long)blockIdx.x * 256 + threadIdx.x;
    long long e = tid >> 3;
    if (e >= E) return;
    int j = (int)(tid & 7);
    int r = __builtin_nontemporal_load(rows + e);
    int c = __builtin_nontemporal_load(cols + e);
    int t = __builtin_nontemporal_load(et + e);
    float wt = w[t];
    unsigned px = xT[(size_t)c * 8 + j];
    float x0 = bf2f((unsigned short)(px & 0xffffu));
    float x1 = bf2f((unsigned short)(px >> 16));
    unsigned short b0 = f2bf(wt * x0);
    unsigned short b1 = f2bf(wt * x1);
    unsigned data = (unsigned)b0 | ((unsigned)b1 << 16);
    unsigned short* dst = outT + ((size_t)r * 16 + 2 * j);
    asm volatile("global_atomic_pk_add_bf16 %0, %1, off"
                 :: "v"(dst), "v"(data) : "memory");
}

__global__ __launch_bounds__(256) void k_transpose_out(const unsigned* __restrict__ outT,
                                                       float* __restrict__ out) {
    int r = blockIdx.x * 256 + threadIdx.x;
    if (r >= NROW) return;
    const uint4* src = reinterpret_cast<const uint4*>(outT + (size_t)r * 8);
    uint4 v0 = src[0], v1 = src[1];
    unsigned p[8] = {v0.x, v0.y, v0.z, v0.w, v1.x, v1.y, v1.z, v1.w};
#pragma unroll
    for (int b = 0; b < 8; ++b) {
        out[(size_t)(2 * b)     * NROW + r] = bf2f((unsigned short)(p[b] & 0xffffu));
        out[(size_t)(2 * b + 1) * NROW + r] = bf2f((unsigned short)(p[b] >> 16));
    }
}

extern "C" void kernel_launch(void* const* d_in, const int* in_sizes, int n_in,
                              void* d_out, int out_size, void* d_ws, size_t ws_size,
                              hipStream_t stream) {
    const float* x    = (const float*)d_in[0];
    const float* w    = (const float*)d_in[1];
    const int*   rows = (const int*)d_in[2];
    const int*   cols = (const int*)d_in[3];
    const int*   et   = (const int*)d_in[4];
    const int    E    = in_sizes[2];

    float* out = (float*)d_out;

    // ws layout: xT bf16 [25.6MB] | recA u32 [4E] | recB u16 [2E] | aux
    size_t xT_b     = (size_t)NCOL * 8 * 4;           // 25,600,000
    size_t recA_off = xT_b;
    size_t recB_off = recA_off + (size_t)E * 4;
    size_t aux_off  = (recB_off + (size_t)E * 2 + 15) & ~(size_t)15;
    size_t needed   = aux_off + (size_t)(PBINS + (PBINS + 1) + PBINS) * 4;

    unsigned* xT = (unsigned*)d_ws;

    if (ws_size >= needed) {
        unsigned*       recA   = (unsigned*)((char*)d_ws + recA_off);
        unsigned short* recB   = (unsigned short*)((char*)d_ws + recB_off);
        unsigned*       gcount = (unsigned*)((char*)d_ws + aux_off);
        unsigned*       offs   = gcount + PBINS;
        unsigned*       cursor = offs + PBINS + 1;

        hipMemsetAsync(gcount, 0, (size_t)PBINS * 4, stream);
        k_transpose_x<<<NCOL / 256, 256, 0, stream>>>(x, xT);

        int pblocks = (E + PR - 1) / PR;
        k_hist<<<pblocks, 1024, 0, stream>>>(rows, gcount, E);
        k_scan<<<1, 1024, 0, stream>>>(gcount, offs, cursor);
        k_part<<<pblocks, 1024, 0, stream>>>(rows, cols, et, cursor, recA, recB, E);
        k_pull<<<NBIN, 1024, 0, stream>>>(offs, recA, recB, w, xT, out);
    } else {
        // fallback: pk_add_bf16 atomic scatter (51.2MB ws)
        unsigned short* outT = (unsigned short*)d_ws;
        unsigned*       xT2  = (unsigned*)((char*)d_ws + (size_t)NROW * BNUM * 2);

        hipMemsetAsync(outT, 0, (size_t)NROW * BNUM * 2, stream);
        k_transpose_x<<<NCOL / 256, 256, 0, stream>>>(x, xT2);

        long long total = (long long)E * 8;
        int blocks = (int)((total + 255) / 256);
        k_scatter<<<blocks, 256, 0, stream>>>(rows, cols, et, w, xT2, outT, E);
        k_transpose_out<<<NROW / 256, 256, 0, stream>>>((const unsigned*)outT, out);
    }
}

// Round 4
// 530.626 us; speedup vs baseline: 1.1625x; 1.1625x over previous
//
#include <hip/hip_runtime.h>

// GraphConv: B=16, S=50000, FIN=FOUT=16, T=64, E=8M
// R4: R3 post-mortem — k_part's 965MB WRITE (ideal 48MB) = per-RUN
// line-granular RFO+writeback (2M runs of ~16B at arbitrary offsets,
// cross-XCD). Fix geometry: 1024-row bins (782, shift key) -> runs ~10.5
// recs, part LDS 100KB; drop NT on flush so L2 can combine; pull goes
// 1 thread/row (1024 = block size), reloads recs (cached) instead of
// register-held -> 79KB LDS -> 2 blocks/CU.
#define BNUM 16
#define NCOL 800000   // S*FIN
#define NROW 800000   // S*FOUT
#define RPB  1024     // rows per bin (pull tile == block size)
#define NBIN 782      // ceil(NROW/RPB)
#define HB   1024     // padded bin count (power of 2, 10-bit key)
#define PBINS 2048    // aux sizing (scan kernel reads 2048 padded)
#define PR   8192     // edges per k_part/k_hist block
#define CAP  11264    // pull capacity (mean 10240, +10 sigma)

// ---- bf16 <-> f32 helpers (bit-exact RNE) ----
__device__ __forceinline__ unsigned short f2bf(float f) {
    unsigned u = __float_as_uint(f);
    unsigned r = (u + 0x7fffu + ((u >> 16) & 1u)) >> 16;   // round-nearest-even
    return (unsigned short)r;
}
__device__ __forceinline__ float bf2f(unsigned short h) {
    return __uint_as_float(((unsigned)h) << 16);
}

// ballot-based equal-key mask + rank within group (wave-parallel, no atomics)
template <int BITS>
__device__ __forceinline__ void brank(unsigned key, bool v, int lane,
                                      int& rank, int& gsz) {
    unsigned long long vm = __ballot(v);
    unsigned long long eq = ~0ull;
#pragma unroll
    for (int b = 0; b < BITS; ++b) {
        unsigned long long bb = __ballot((key >> b) & 1u);
        eq &= ((key >> b) & 1u) ? bb : ~bb;
    }
    eq &= vm;
    rank = __popcll(eq & ((1ull << lane) - 1ull));
    gsz  = __popcll(eq);
}

// x [16][800000] f32 (b-major) -> xT [800000][16] bf16 (c-major, 32B per c)
__global__ __launch_bounds__(256) void k_transpose_x(const float* __restrict__ x,
                                                     unsigned* __restrict__ xT) {
    int c = blockIdx.x * 256 + threadIdx.x;
    if (c >= NCOL) return;
    unsigned p[8];
#pragma unroll
    for (int b = 0; b < 8; ++b) {
        float lo = x[(size_t)(2 * b)     * NCOL + c];
        float hi = x[(size_t)(2 * b + 1) * NCOL + c];
        p[b] = (unsigned)f2bf(lo) | ((unsigned)f2bf(hi) << 16);
    }
    uint4* dst = reinterpret_cast<uint4*>(xT + (size_t)c * 8);
    dst[0] = make_uint4(p[0], p[1], p[2], p[3]);
    dst[1] = make_uint4(p[4], p[5], p[6], p[7]);
}

// Ballot-based per-wave histogram of row bins (atomic-free per element).
__global__ __launch_bounds__(1024) void k_hist(const int* __restrict__ rows,
                                               unsigned* __restrict__ gcount,
                                               int E) {
    __shared__ unsigned short h16[16][HB];      // 32KB wave-private
    int tid = threadIdx.x, lane = tid & 63, wv = tid >> 6;
    unsigned* hw = (unsigned*)h16;
    for (int i = tid; i < 16 * HB / 2; i += 1024) hw[i] = 0u;
    __syncthreads();
    int c0 = blockIdx.x * PR;
#pragma unroll
    for (int c = 0; c < 8; ++c) {
        int idx = c0 + c * 1024 + tid;
        bool v = idx < E;
        unsigned key = 0u;
        if (v) key = (unsigned)__builtin_nontemporal_load(rows + idx) >> 10;
        int rank, gsz;
        brank<10>(key, v, lane, rank, gsz);
        if (v && rank == 0)
            h16[wv][key] = (unsigned short)(h16[wv][key] + (unsigned)gsz);
    }
    __syncthreads();
    for (int b = tid; b < HB; b += 1024) {
        unsigned s = 0;
#pragma unroll
        for (int ww = 0; ww < 16; ++ww) s += h16[ww][b];
        if (s) atomicAdd(&gcount[b], s);
    }
}

// Exclusive scan of 2048 (zero-padded) counts, offs + cursor init.
__global__ __launch_bounds__(1024) void k_scan(const unsigned* __restrict__ gcount,
                                               unsigned* __restrict__ offs,
                                               unsigned* __restrict__ cursor) {
    __shared__ unsigned wsum[16];
    int t = threadIdx.x;
    unsigned a0 = gcount[2 * t], a1 = gcount[2 * t + 1];
    unsigned ts = a0 + a1, incl = ts;
    for (int off = 1; off < 64; off <<= 1) {
        unsigned n = __shfl_up(incl, off, 64);
        if ((t & 63) >= off) incl += n;
    }
    if ((t & 63) == 63) wsum[t >> 6] = incl;
    __syncthreads();
    unsigned pre = 0;
    for (int k = 0; k < (t >> 6); ++k) pre += wsum[k];
    unsigned ex = pre + incl - ts;
    offs[2 * t] = ex;       offs[2 * t + 1] = ex + a0;
    cursor[2 * t] = ex;     cursor[2 * t + 1] = ex + a0;
    if (t == 1023) offs[2048] = pre + incl;
}

// Ballot multisplit by bin = row>>10 (atomic-free ranking). Edges in
// registers; phase A counts, block scan, phase B places into LDS sorted
// order, run-contiguous flush (plain stores: L2 write-combining).
// recA = col|type<<20, recB = row & 1023.
__global__ __launch_bounds__(1024) void k_part(const int* __restrict__ rows,
                                               const int* __restrict__ cols,
                                               const int* __restrict__ et,
                                               unsigned* __restrict__ cursor,
                                               unsigned* __restrict__ recA,
                                               unsigned short* __restrict__ recB,
                                               int E) {
    __shared__ unsigned short h16[16][HB];      // 32KB wave-private hist/cursor
    __shared__ unsigned srtP[PR];               // 32KB payload (col|type)
    __shared__ unsigned srtK[PR];               // 32KB raw row
    __shared__ unsigned gadj[HB];               // 4KB  gbase - lofs
    __shared__ unsigned wsum[16];

    int tid = threadIdx.x, lane = tid & 63, wv = tid >> 6;
    int c0 = blockIdx.x * PR;
    unsigned* hw = (unsigned*)h16;
    for (int i = tid; i < 16 * HB / 2; i += 1024) hw[i] = 0u;
    __syncthreads();

    unsigned er[8], ec[8];
#pragma unroll
    for (int c = 0; c < 8; ++c) {
        int idx = c0 + c * 1024 + tid;
        if (idx < E) {
            int r  = __builtin_nontemporal_load(rows + idx);
            int cc = __builtin_nontemporal_load(cols + idx);
            int ty = __builtin_nontemporal_load(et + idx);
            er[c] = (unsigned)r;
            ec[c] = (unsigned)cc | ((unsigned)ty << 20);
        } else {
            er[c] = 0xFFFFFFFFu;
        }
    }

    // phase A: ballot-ranked wave-private histogram
#pragma unroll
    for (int c = 0; c < 8; ++c) {
        bool v = er[c] != 0xFFFFFFFFu;
        unsigned key = (er[c] >> 10) & (HB - 1);
        int rank, gsz;
        brank<10>(key, v, lane, rank, gsz);
        if (v && rank == 0)
            h16[wv][key] = (unsigned short)(h16[wv][key] + (unsigned)gsz);
    }
    __syncthreads();

    // per-bin wave prefix + block scan + global reservation (1 bin/thread)
    {
        int b = tid;
        unsigned t0 = 0;
#pragma unroll
        for (int ww = 0; ww < 16; ++ww) {
            unsigned a = h16[ww][b]; h16[ww][b] = (unsigned short)t0; t0 += a;
        }
        unsigned incl = t0;
        for (int off = 1; off < 64; off <<= 1) {
            unsigned n = __shfl_up(incl, off, 64);
            if ((tid & 63) >= off) incl += n;
        }
        if ((tid & 63) == 63) wsum[tid >> 6] = incl;
        __syncthreads();
        unsigned pre = 0;
        for (int k = 0; k < (tid >> 6); ++k) pre += wsum[k];
        unsigned ex = pre + incl - t0;
        gadj[b] = (t0 ? atomicAdd(&cursor[b], t0) : 0u) - ex;
#pragma unroll
        for (int ww = 0; ww < 16; ++ww)
            h16[ww][b] = (unsigned short)(h16[ww][b] + ex);
    }
    __syncthreads();

    // phase B: replay, place into LDS sorted order
#pragma unroll
    for (int c = 0; c < 8; ++c) {
        bool v = er[c] != 0xFFFFFFFFu;
        unsigned key = (er[c] >> 10) & (HB - 1);
        int rank, gsz;
        brank<10>(key, v, lane, rank, gsz);
        unsigned cur = h16[wv][key];
        if (v && rank == 0)
            h16[wv][key] = (unsigned short)(cur + (unsigned)gsz);
        if (v) {
            unsigned d = cur + (unsigned)rank;
            srtP[d] = ec[c];
            srtK[d] = er[c];
        }
    }
    __syncthreads();

    // flush: consecutive LDS slots within a bin run -> consecutive global
    // dst. PLAIN stores (no NT): partial lines stay in L2 for combining.
    int tot = min(PR, E - c0);
    for (int j = tid; j < tot; j += 1024) {
        unsigned rr = srtK[j], key = rr >> 10;
        unsigned dst = gadj[key] + (unsigned)j;
        recA[dst] = srtP[j];
        recB[dst] = (unsigned short)(rr & 1023u);
    }
}

__device__ __forceinline__ void fma8(float* a, float wt, uint4 v, int base) {
    a[base + 0] += wt * bf2f((unsigned short)(v.x & 0xffffu));
    a[base + 1] += wt * bf2f((unsigned short)(v.x >> 16));
    a[base + 2] += wt * bf2f((unsigned short)(v.y & 0xffffu));
    a[base + 3] += wt * bf2f((unsigned short)(v.y >> 16));
    a[base + 4] += wt * bf2f((unsigned short)(v.z & 0xffffu));
    a[base + 5] += wt * bf2f((unsigned short)(v.z >> 16));
    a[base + 6] += wt * bf2f((unsigned short)(v.w & 0xffffu));
    a[base + 7] += wt * bf2f((unsigned short)(v.w >> 16));
}

// One block per 1024-row bin: ballot counting-sort by lrow (atomic-free),
// then 1 thread/row register accumulate, coalesced store. Recs are
// (re)loaded with cached loads: phase B hits L2.
__global__ __launch_bounds__(1024) void k_pull(const unsigned* __restrict__ offs,
                                               const unsigned* __restrict__ recA,
                                               const unsigned short* __restrict__ recB,
                                               const float* __restrict__ wt_tab,
                                               const unsigned* __restrict__ xT,
                                               float* __restrict__ out) {
    __shared__ unsigned short h16[16][RPB];    // 32KB wave-private hist/cursor
    __shared__ unsigned srt[CAP];              // 44KB sorted payload
    __shared__ unsigned short ptr_[RPB + 1];   // 2KB row offsets
    __shared__ unsigned wsum[16];

    int tid = threadIdx.x, lane = tid & 63, wv = tid >> 6;
    int b   = blockIdx.x;
    int beg = (int)offs[b];
    int end = (int)offs[b + 1];
    int n   = min(end - beg, CAP);
    int nr  = (n + 1023) >> 10;                // rounds (<=11)

    unsigned* hw = (unsigned*)h16;
    for (int i = tid; i < 16 * RPB / 2; i += 1024) hw[i] = 0u;
    __syncthreads();

    // phase A: ballot histogram by lrow (10 bits) — cached loads
    for (int c = 0; c < nr; ++c) {
        int idx = c * 1024 + tid;
        bool v = idx < n;
        unsigned key = 0u;
        if (v) key = recB[beg + idx] & (RPB - 1u);
        int rank, gsz;
        brank<10>(key, v, lane, rank, gsz);
        if (v && rank == 0)
            h16[wv][key] = (unsigned short)(h16[wv][key] + (unsigned)gsz);
    }
    __syncthreads();

    // scan 1024 bins (1/thread): wave prefix into h16, block scan -> ptr_
    {
        unsigned t0 = 0;
#pragma unroll
        for (int ww = 0; ww < 16; ++ww) {
            unsigned a = h16[ww][tid]; h16[ww][tid] = (unsigned short)t0; t0 += a;
        }
        unsigned incl = t0;
        for (int off = 1; off < 64; off <<= 1) {
            unsigned m = __shfl_up(incl, off, 64);
            if ((tid & 63) >= off) incl += m;
        }
        if ((tid & 63) == 63) wsum[tid >> 6] = incl;
        __syncthreads();
        unsigned pre = 0;
        for (int k = 0; k < (tid >> 6); ++k) pre += wsum[k];
        unsigned ex = pre + incl - t0;
        ptr_[tid] = (unsigned short)ex;
        if (tid == 1023) ptr_[RPB] = (unsigned short)n;
#pragma unroll
        for (int ww = 0; ww < 16; ++ww)
            h16[ww][tid] = (unsigned short)(h16[ww][tid] + ex);
    }
    __syncthreads();

    // phase B: reload (L2-hot), place payload into LDS sorted order
    for (int c = 0; c < nr; ++c) {
        int idx = c * 1024 + tid;
        bool v = idx < n;
        unsigned key = 0u, pay = 0u;
        if (v) {
            key = recB[beg + idx] & (RPB - 1u);
            pay = recA[beg + idx];
        }
        int rank, gsz;
        brank<10>(key, v, lane, rank, gsz);
        unsigned cur = h16[wv][key];
        if (v && rank == 0)
            h16[wv][key] = (unsigned short)(cur + (unsigned)gsz);
        if (v) srt[cur + (unsigned)rank] = pay;
    }
    __syncthreads();

    // gather: 1 thread per row, register accumulate, 2-deep pipeline
    bool ovf = (end - beg) > CAP;
    int r = tid;
    float a[16];
#pragma unroll
    for (int k = 0; k < 16; ++k) a[k] = 0.f;
    {
        int p0 = (int)ptr_[r];
        int p1 = (int)ptr_[r + 1];
        uint4 lo = make_uint4(0, 0, 0, 0), hi = lo;
        unsigned u = 0u;
        int p = p0;
        if (p < p1) {
            u = srt[p];
            const uint4* q = reinterpret_cast<const uint4*>(xT + (size_t)(u & 0xFFFFFu) * 8);
            lo = q[0]; hi = q[1];
        }
        while (p < p1) {
            int pn = p + 1;
            unsigned un = 0u;
            uint4 lon = make_uint4(0, 0, 0, 0), hin = lon;
            if (pn < p1) {
                un = srt[pn];
                const uint4* qn = reinterpret_cast<const uint4*>(xT + (size_t)(un & 0xFFFFFu) * 8);
                lon = qn[0]; hin = qn[1];
            }
            float wt = wt_tab[u >> 20];
            fma8(a, wt, lo, 0);
            fma8(a, wt, hi, 8);
            u = un; lo = lon; hi = hin; p = pn;
        }
    }
    int gr = b * RPB + r;
    if (gr < NROW) {
        if (!ovf) {
#pragma unroll
            for (int k = 0; k < 16; ++k)
                __builtin_nontemporal_store(a[k], out + (size_t)k * NROW + gr);
        } else {
#pragma unroll
            for (int k = 0; k < 16; ++k)
                out[(size_t)k * NROW + gr] = a[k];   // plain: ordered vs atomics
        }
    }

    // overflow safety (statistically never): atomic top-up after store
    if (ovf) {
        __syncthreads();
        for (int i = beg + CAP + tid; i < end; i += 1024) {
            unsigned uu = recA[i];
            unsigned lr = recB[i];
            int gr2 = b * RPB + (int)lr;
            float wt = wt_tab[uu >> 20];
            const uint4* q = reinterpret_cast<const uint4*>(xT + (size_t)(uu & 0xFFFFFu) * 8);
            uint4 vlo = q[0], vhi = q[1];
            float tmp[16];
#pragma unroll
            for (int k = 0; k < 16; ++k) tmp[k] = 0.f;
            fma8(tmp, wt, vlo, 0);
            fma8(tmp, wt, vhi, 8);
#pragma unroll
            for (int k = 0; k < 16; ++k)
                atomicAdd(out + (size_t)k * NROW + gr2, tmp[k]);
        }
    }
}

// ---------------- fallback path (old atomic scatter, needs only 51.2MB) ----

__global__ __launch_bounds__(256) void k_scatter(const int* __restrict__ rows,
                                                 const int* __restrict__ cols,
                                                 const int* __restrict__ et,
                                                 const float* __restrict__ w,
                                                 const unsigned* __restrict__ xT,
                                                 unsigned short* __restrict__ outT,
                                                 int E) {
    long long tid = (long long)blockIdx.x * 256 + threadIdx.x;
    long long e = tid >> 3;
    if (e >= E) return;
    int j = (int)(tid & 7);
    int r = __builtin_nontemporal_load(rows + e);
    int c = __builtin_nontemporal_load(cols + e);
    int t = __builtin_nontemporal_load(et + e);
    float wt = w[t];
    unsigned px = xT[(size_t)c * 8 + j];
    float x0 = bf2f((unsigned short)(px & 0xffffu));
    float x1 = bf2f((unsigned short)(px >> 16));
    unsigned short b0 = f2bf(wt * x0);
    unsigned short b1 = f2bf(wt * x1);
    unsigned data = (unsigned)b0 | ((unsigned)b1 << 16);
    unsigned short* dst = outT + ((size_t)r * 16 + 2 * j);
    asm volatile("global_atomic_pk_add_bf16 %0, %1, off"
                 :: "v"(dst), "v"(data) : "memory");
}

__global__ __launch_bounds__(256) void k_transpose_out(const unsigned* __restrict__ outT,
                                                       float* __restrict__ out) {
    int r = blockIdx.x * 256 + threadIdx.x;
    if (r >= NROW) return;
    const uint4* src = reinterpret_cast<const uint4*>(outT + (size_t)r * 8);
    uint4 v0 = src[0], v1 = src[1];
    unsigned p[8] = {v0.x, v0.y, v0.z, v0.w, v1.x, v1.y, v1.z, v1.w};
#pragma unroll
    for (int b = 0; b < 8; ++b) {
        out[(size_t)(2 * b)     * NROW + r] = bf2f((unsigned short)(p[b] & 0xffffu));
        out[(size_t)(2 * b + 1) * NROW + r] = bf2f((unsigned short)(p[b] >> 16));
    }
}

extern "C" void kernel_launch(void* const* d_in, const int* in_sizes, int n_in,
                              void* d_out, int out_size, void* d_ws, size_t ws_size,
                              hipStream_t stream) {
    const float* x    = (const float*)d_in[0];
    const float* w    = (const float*)d_in[1];
    const int*   rows = (const int*)d_in[2];
    const int*   cols = (const int*)d_in[3];
    const int*   et   = (const int*)d_in[4];
    const int    E    = in_sizes[2];

    float* out = (float*)d_out;

    // ws layout: xT bf16 [25.6MB] | recA u32 [4E] | recB u16 [2E] | aux
    size_t xT_b     = (size_t)NCOL * 8 * 4;           // 25,600,000
    size_t recA_off = xT_b;
    size_t recB_off = recA_off + (size_t)E * 4;
    size_t aux_off  = (recB_off + (size_t)E * 2 + 15) & ~(size_t)15;
    size_t needed   = aux_off + (size_t)(PBINS + (PBINS + 1) + PBINS) * 4;

    unsigned* xT = (unsigned*)d_ws;

    if (ws_size >= needed) {
        unsigned*       recA   = (unsigned*)((char*)d_ws + recA_off);
        unsigned short* recB   = (unsigned short*)((char*)d_ws + recB_off);
        unsigned*       gcount = (unsigned*)((char*)d_ws + aux_off);
        unsigned*       offs   = gcount + PBINS;
        unsigned*       cursor = offs + PBINS + 1;

        hipMemsetAsync(gcount, 0, (size_t)PBINS * 4, stream);
        k_transpose_x<<<NCOL / 256, 256, 0, stream>>>(x, xT);

        int pblocks = (E + PR - 1) / PR;
        k_hist<<<pblocks, 1024, 0, stream>>>(rows, gcount, E);
        k_scan<<<1, 1024, 0, stream>>>(gcount, offs, cursor);
        k_part<<<pblocks, 1024, 0, stream>>>(rows, cols, et, cursor, recA, recB, E);
        k_pull<<<NBIN, 1024, 0, stream>>>(offs, recA, recB, w, xT, out);
    } else {
        // fallback: pk_add_bf16 atomic scatter (51.2MB ws)
        unsigned short* outT = (unsigned short*)d_ws;
        unsigned*       xT2  = (unsigned*)((char*)d_ws + (size_t)NROW * BNUM * 2);

        hipMemsetAsync(outT, 0, (size_t)NROW * BNUM * 2, stream);
        k_transpose_x<<<NCOL / 256, 256, 0, stream>>>(x, xT2);

        long long total = (long long)E * 8;
        int blocks = (int)((total + 255) / 256);
        k_scatter<<<blocks, 256, 0, stream>>>(rows, cols, et, w, xT2, outT, E);
        k_transpose_out<<<NROW / 256, 256, 0, stream>>>((const unsigned*)outT, out);
    }
}